// Round 2
// baseline (280.431 us; speedup 1.0000x reference)
//
#include <hip/hip_runtime.h>

typedef unsigned short u16;
typedef __bf16 bf16x8 __attribute__((ext_vector_type(8)));
typedef float f32x4 __attribute__((ext_vector_type(4)));

__device__ __forceinline__ u16 f2b(float f) {
    unsigned u = __builtin_bit_cast(unsigned, f);
    unsigned r = (u + 0x7fffu + ((u >> 16) & 1u)) >> 16;
    return (u16)r;
}
#if __has_builtin(__builtin_amdgcn_cvt_pk_bf16_f32)
typedef __bf16 bf16x2_t __attribute__((ext_vector_type(2)));
__device__ __forceinline__ unsigned pk2(float a, float b) {
    return __builtin_bit_cast(unsigned, __builtin_amdgcn_cvt_pk_bf16_f32(a, b));
}
#else
__device__ __forceinline__ unsigned pk2(float a, float b) {
    return (unsigned)f2b(a) | ((unsigned)f2b(b) << 16);
}
#endif
#if __has_builtin(__builtin_amdgcn_exp2f)
#define EXP2F(x) __builtin_amdgcn_exp2f(x)
#else
#define EXP2F(x) exp2f(x)
#endif

// async global->LDS 16B/lane; lds dest is wave-uniform base (+lane*16 by HW)
__device__ __forceinline__ void gl_lds16(const u16* g, u16* l) {
    __builtin_amdgcn_global_load_lds(
        (const __attribute__((address_space(1))) unsigned*)(const void*)g,
        (__attribute__((address_space(3))) unsigned*)(void*)l, 16, 0, 0);
}

// ---------------- RoPE cos/sin table: tab[s*32+d] = (cos, sin)(s * 10000^(-d/32)) ----
__global__ __launch_bounds__(256) void k_rope_table(float2* __restrict__ tab) {
    int i = blockIdx.x * 256 + threadIdx.x;  // 0..65535
    int s = i >> 5, d = i & 31;
    const float C0 = 0.4152410118609203f;  // log2(10000)/32
    float inv_freq = exp2f(-C0 * (float)d);
    float sn, cs;
    sincosf((float)s * inv_freq, &sn, &cs);
    tab[i] = make_float2(cs, sn);
}

// ---------------- convert x (fp32 -> bf16), 8 elems/thread ----------------
__global__ __launch_bounds__(256) void k_convert(const float* __restrict__ in,
                                                 u16* __restrict__ out, int n8) {
    int i = blockIdx.x * 256 + threadIdx.x;
    if (i >= n8) return;
    const float4* p = (const float4*)(in + (size_t)i * 8);
    float4 a = p[0], b = p[1];
    u16 t[8] = {f2b(a.x), f2b(a.y), f2b(a.z), f2b(a.w),
                f2b(b.x), f2b(b.y), f2b(b.z), f2b(b.w)};
    *(uint4*)(out + (size_t)i * 8) = *(const uint4*)t;
}

// -------- transpose + convert: in[R][C] fp32 -> out[C][R] bf16, 64x64 tiles --------
__global__ __launch_bounds__(256) void k_transpose_bf16(const float* __restrict__ in,
                                                        u16* __restrict__ out,
                                                        int R, int C) {
    __shared__ u16 tile[64][72];
    int tc = blockIdx.x * 64;
    int tr = blockIdx.y * 64;
    for (int i = threadIdx.x; i < 4096; i += 256) {
        int r = i >> 6, c = i & 63;
        tile[c][r] = f2b(in[(size_t)(tr + r) * C + tc + c]);
    }
    __syncthreads();
    for (int i = threadIdx.x; i < 4096; i += 256) {
        int r = i >> 6, c = i & 63;
        out[(size_t)(tc + r) * R + tr + c] = tile[r][c];
    }
}

// ------- 128x128xK bf16 MFMA mainloop, BK=64 (2x32 stages per barrier pair) -------
// LDS: two 128x32 subtiles per operand (32 KB total), unpadded for DMA deposit.
__device__ __forceinline__ void gemm_mainloop(const u16* __restrict__ Ab,
                                              const u16* __restrict__ Bb, int K,
                                              u16* As, u16* Bs, int tid,
                                              f32x4 (&acc)[4][4]) {
    const int wave = tid >> 6, lane = tid & 63;
    const int col = lane & 15, quad = lane >> 4;
    const int wm = wave >> 1, wn = wave & 1;
    const int lrow = lane >> 2, lk = (lane & 3) * 8;
    u16* ldsA0 = As + (wave * 16) * 32;  // wave-uniform segment bases
    u16* ldsA1 = As + (64 + wave * 16) * 32;
    u16* ldsB0 = Bs + (wave * 16) * 32;
    u16* ldsB1 = Bs + (64 + wave * 16) * 32;
    const u16* gA0 = Ab + (size_t)(wave * 16 + lrow) * K + lk;
    const u16* gA1 = gA0 + (size_t)64 * K;
    const u16* gB0 = Bb + (size_t)(wave * 16 + lrow) * K + lk;
    const u16* gB1 = gB0 + (size_t)64 * K;
    for (int k0 = 0; k0 < K; k0 += 64) {
        if (k0) __syncthreads();
#pragma unroll
        for (int kh = 0; kh < 2; ++kh) {
            int ko = k0 + kh * 32;
            gl_lds16(gA0 + ko, ldsA0 + kh * 4096);
            gl_lds16(gA1 + ko, ldsA1 + kh * 4096);
            gl_lds16(gB0 + ko, ldsB0 + kh * 4096);
            gl_lds16(gB1 + ko, ldsB1 + kh * 4096);
        }
        __syncthreads();  // compiler drains vmcnt(0) before s_barrier
#pragma unroll
        for (int kh = 0; kh < 2; ++kh) {
            bf16x8 af[4], bfr[4];
#pragma unroll
            for (int mt = 0; mt < 4; ++mt)
                af[mt] = *(const bf16x8*)(As + kh * 4096 +
                                          (wm * 64 + mt * 16 + col) * 32 + quad * 8);
#pragma unroll
            for (int nt = 0; nt < 4; ++nt)
                bfr[nt] = *(const bf16x8*)(Bs + kh * 4096 +
                                           (wn * 64 + nt * 16 + col) * 32 + quad * 8);
#pragma unroll
            for (int mt = 0; mt < 4; ++mt)
#pragma unroll
                for (int nt = 0; nt < 4; ++nt)
                    acc[mt][nt] = __builtin_amdgcn_mfma_f32_16x16x32_bf16(
                        af[mt], bfr[nt], acc[mt][nt], 0, 0, 0);
        }
    }
}

// ---------------- QKV GEMM + bias + RoPE + head reshape ----------------
// Q additionally prescaled by 0.125*log2(e) so attention softmax is pure exp2.
// Region (q/k/v) is block-uniform: 128-col blocks never straddle a 1024 boundary.
// Q/K epilogue: RoPE via precomputed table, stage rotated bf16 tile in LDS
// (reusing the 32KB mainloop buffers, 16B-chunk XOR swizzle), then 16B/lane
// coalesced stores. V epilogue: 4 consecutive-s values packed per 8B store.
__global__ __launch_bounds__(256) void k_gemm_qkv_rope(
    const u16* __restrict__ A, const u16* __restrict__ Bt,
    const float* __restrict__ bias, const float2* __restrict__ tab,
    u16* __restrict__ Qr, u16* __restrict__ Kr, u16* __restrict__ Vt) {
    __shared__ __align__(16) u16 smem[16384];  // mainloop: As|Bs ; epilogue: 128x128 tile
    u16* As = smem;
    u16* Bs = smem + 8192;
    const int K = 1024;
    int tid = threadIdx.x;
    int lane = tid & 63, wave = tid >> 6;
    int col = lane & 15, quad = lane >> 4;
    int wm = wave >> 1, wn = wave & 1;
    int mBase = blockIdx.y * 128;
    int nBase = blockIdx.x * 128;
    f32x4 acc[4][4] = {};
    gemm_mainloop(A + (size_t)mBase * K, Bt + (size_t)nBase * K, K, As, Bs, tid, acc);

    int region = nBase >> 10;  // 0=q, 1=k, 2=v (block-uniform)
    int n64 = nBase + wn * 64;
    int h = (n64 & 1023) >> 6;
    if (region < 2) {
        __syncthreads();  // mainloop LDS reads complete before tile overwrite
        float qs = (region == 0) ? 0.18033688011112042f : 1.0f;  // 0.125*log2(e)
#pragma unroll
        for (int nt = 0; nt < 2; ++nt) {
            int d1 = nt * 16 + col;  // 0..31
            float b1 = bias[n64 + d1];
            float b2 = bias[n64 + d1 + 32];
            int nl = wn * 64 + nt * 16 + col;
#pragma unroll
            for (int mt = 0; mt < 4; ++mt) {
                int mlb = wm * 64 + mt * 16 + quad * 4;
#pragma unroll
                for (int r = 0; r < 4; ++r) {
                    int mloc = mlb + r;
                    int s = (mBase + mloc) & 2047;
                    float2 t = tab[s * 32 + d1];
                    float t1 = acc[mt][nt][r] + b1;
                    float t2 = acc[mt][nt + 2][r] + b2;
                    int sw = (mloc & 7) << 3;  // 16B-chunk XOR swizzle
                    smem[mloc * 128 + (nl ^ sw)] = f2b((t1 * t.x - t2 * t.y) * qs);
                    smem[mloc * 128 + ((nl + 32) ^ sw)] = f2b((t2 * t.x + t1 * t.y) * qs);
                }
            }
        }
        __syncthreads();
        u16* outp = (region == 0) ? Qr : Kr;
#pragma unroll
        for (int p = 0; p < 8; ++p) {
            int lin = p * 256 + tid;   // 0..2047
            int mloc = lin >> 4;       // 0..127
            int c8 = (lin & 15) << 3;  // 0..120
            uint4 v = *(const uint4*)(smem + mloc * 128 + (c8 ^ ((mloc & 7) << 3)));
            int m = mBase + mloc;
            int s = m & 2047, b = m >> 11;
            int ng = (nBase & 1023) + c8;  // col within region
            *(uint4*)(Qr == outp || Kr == outp
                          ? outp + ((size_t)((b * 16 + (ng >> 6)) * 2048 + s)) * 64 +
                                (ng & 63)
                          : outp) = v;
        }
    } else {
        int b = mBase >> 11;     // block-uniform (mBase multiple of 128)
        int sb0 = mBase & 2047;  // s of tile row 0
#pragma unroll
        for (int nt = 0; nt < 4; ++nt) {
            int d = nt * 16 + col;
            float bv = bias[n64 + d];
            u16* vrow = Vt + ((size_t)((b * 16 + h) * 64 + d)) * 2048;
#pragma unroll
            for (int mt = 0; mt < 4; ++mt) {
                int s = sb0 + wm * 64 + mt * 16 + quad * 4;  // 4-aligned
                uint2 w;
                w.x = pk2(acc[mt][nt][0] + bv, acc[mt][nt][1] + bv);
                w.y = pk2(acc[mt][nt][2] + bv, acc[mt][nt][3] + bv);
                *(uint2*)(vrow + s) = w;
            }
        }
    }
}

// ------------- flash attention (causal, transposed, permuted-row, 128q/block) -------------
// One qb (128 queries) per block; grid 16x64 = 1024 blocks = 4/CU (was 2/CU).
// XCD-grouped id map: xcd=id&7, head=xcd*8+(seq>>4), qb=15-(seq&15) -- the 16
// blocks sharing one head's K/V land on one XCD's L2; heavy blocks (qb=15,
// 32 iters) dispatch first within each head to reduce tail straggle.
// K/V staging is double-buffered (T14): tile j+1's global loads issue before
// tile j's compute, regs deposit to the other LDS buffer after compute, ONE
// barrier per iter. Load latency hides under QK^T+softmax+PV.
// Wave owns 16-q subtiles at q=qb*128+w*16 (sub0) and +64 (sub1). K/V frags
// read from LDS once per iter, reused by both subtiles. sub0 masked at j==t0,
// inactive at j==t1; sub1 masked at j==t1. Permuted-row QK^T: tile nt reads Ks
// row (nt&1)*32+(col>>2)*8+(nt>>1)*4+(col&3) so lane reg (nt,r) holds key
// (nt&1)*32+quad*8+(nt>>1)*4+r => PV B-frag lane-local. Fixed-max softmax.
__global__ __launch_bounds__(256, 4) void k_attn(const u16* __restrict__ Qr,
                                                 const u16* __restrict__ Kr,
                                                 const u16* __restrict__ Vt,
                                                 u16* __restrict__ O) {
    __shared__ __align__(16) u16 Ks[2][64 * 72];  // [buf][key][d]
    __shared__ __align__(16) u16 Vs[2][64 * 72];  // [buf][d][key]
    int tid = threadIdx.x, wave = tid >> 6, lane = tid & 63;
    int col = lane & 15, quad = lane >> 4;
    int id = blockIdx.x + (blockIdx.y << 4);
    int xcd = id & 7, seq = id >> 3;
    int head = xcd * 8 + (seq >> 4);  // 0..63, bijective over 1024 blocks
    int qb = 15 - (seq & 15);
    int b = head >> 4, h = head & 15;
    size_t headQ = (size_t)head * 2048 * 64;
    size_t headV = (size_t)head * 64 * 2048;
    int r0 = tid >> 3, kc = tid & 7;
    int rb72 = ((col >> 2) * 8 + (col & 3)) * 72;  // permuted row base

    int t0 = 2 * qb, t1 = t0 + 1;
    int myq0 = qb * 128 + wave * 16 + col;
    int myq1 = myq0 + 64;
    const u16* qp0 = Qr + headQ + (size_t)myq0 * 64;
    const u16* qp1 = Qr + headQ + (size_t)myq1 * 64;
    bf16x8 aq00 = *(const bf16x8*)(qp0 + quad * 8);
    bf16x8 aq01 = *(const bf16x8*)(qp0 + 32 + quad * 8);
    bf16x8 aq10 = *(const bf16x8*)(qp1 + quad * 8);
    bf16x8 aq11 = *(const bf16x8*)(qp1 + 32 + quad * 8);
    f32x4 o0[4] = {}, o1[4] = {};
    float l0 = 0.f, l1 = 0.f;

    const u16* kg = Kr + headQ + (size_t)r0 * 64 + kc * 8;
    const u16* vg = Vt + headV + (size_t)r0 * 2048 + kc * 8;
    // prologue: stage tile 0 into buf 0
    {
        uint4 kr0 = *(const uint4*)kg;
        uint4 kr1 = *(const uint4*)(kg + 32 * 64);
        uint4 vr0 = *(const uint4*)vg;
        uint4 vr1 = *(const uint4*)(vg + 32 * 2048);
        *(uint4*)(Ks[0] + r0 * 72 + kc * 8) = kr0;
        *(uint4*)(Ks[0] + (r0 + 32) * 72 + kc * 8) = kr1;
        *(uint4*)(Vs[0] + r0 * 72 + kc * 8) = vr0;
        *(uint4*)(Vs[0] + (r0 + 32) * 72 + kc * 8) = vr1;
    }
    __syncthreads();

    for (int j = 0; j <= t1; ++j) {
        int cur = j & 1;
        uint4 kr0, kr1, vr0, vr1;
        if (j < t1) {  // issue next tile's loads; consumed after compute
            const u16* kgn = kg + (size_t)(j + 1) * 64 * 64;
            const u16* vgn = vg + (j + 1) * 64;
            kr0 = *(const uint4*)kgn;
            kr1 = *(const uint4*)(kgn + 32 * 64);
            vr0 = *(const uint4*)vgn;
            vr1 = *(const uint4*)(vgn + 32 * 2048);
        }
        bool d0 = (j <= t0);  // block-uniform
        const u16* KsC = Ks[cur];
        const u16* VsC = Vs[cur];
        f32x4 s0[4], s1[4];
#pragma unroll
        for (int nt = 0; nt < 4; ++nt) {
            const u16* kp = KsC + rb72 + ((nt & 1) * 32 + (nt >> 1) * 4) * 72;
            bf16x8 ak0 = *(const bf16x8*)(kp + quad * 8);
            bf16x8 ak1 = *(const bf16x8*)(kp + 32 + quad * 8);
            if (d0) {
                f32x4 z = {};
                z = __builtin_amdgcn_mfma_f32_16x16x32_bf16(ak0, aq00, z, 0, 0, 0);
                s0[nt] = __builtin_amdgcn_mfma_f32_16x16x32_bf16(ak1, aq01, z, 0, 0, 0);
            }
            f32x4 z = {};
            z = __builtin_amdgcn_mfma_f32_16x16x32_bf16(ak0, aq10, z, 0, 0, 0);
            s1[nt] = __builtin_amdgcn_mfma_f32_16x16x32_bf16(ak1, aq11, z, 0, 0, 0);
        }
        if (j == t0) {  // diagonal for sub0
#pragma unroll
            for (int nt = 0; nt < 4; ++nt) {
                int keyb = j * 64 + (nt & 1) * 32 + quad * 8 + (nt >> 1) * 4;
#pragma unroll
                for (int r = 0; r < 4; ++r)
                    if (keyb + r > myq0) s0[nt][r] = -3.0e38f;
            }
        }
        if (j == t1) {  // diagonal for sub1
#pragma unroll
            for (int nt = 0; nt < 4; ++nt) {
                int keyb = j * 64 + (nt & 1) * 32 + quad * 8 + (nt >> 1) * 4;
#pragma unroll
                for (int r = 0; r < 4; ++r)
                    if (keyb + r > myq1) s1[nt][r] = -3.0e38f;
            }
        }
        unsigned P40[8], P41[8];
        if (d0) {
#pragma unroll
            for (int nt = 0; nt < 4; ++nt) {
                float p0 = EXP2F(s0[nt][0]);
                float p1 = EXP2F(s0[nt][1]);
                float p2 = EXP2F(s0[nt][2]);
                float p3 = EXP2F(s0[nt][3]);
                l0 += (p0 + p1) + (p2 + p3);
                P40[2 * nt] = pk2(p0, p1);
                P40[2 * nt + 1] = pk2(p2, p3);
            }
        }
#pragma unroll
        for (int nt = 0; nt < 4; ++nt) {
            float p0 = EXP2F(s1[nt][0]);
            float p1 = EXP2F(s1[nt][1]);
            float p2 = EXP2F(s1[nt][2]);
            float p3 = EXP2F(s1[nt][3]);
            l1 += (p0 + p1) + (p2 + p3);
            P41[2 * nt] = pk2(p0, p1);
            P41[2 * nt + 1] = pk2(p2, p3);
        }
#pragma unroll
        for (int kk = 0; kk < 2; ++kk) {
            uint4 bw0, bw1;
            bw0.x = P40[2 * kk];
            bw0.y = P40[2 * kk + 1];
            bw0.z = P40[2 * kk + 4];
            bw0.w = P40[2 * kk + 5];
            bw1.x = P41[2 * kk];
            bw1.y = P41[2 * kk + 1];
            bw1.z = P41[2 * kk + 4];
            bw1.w = P41[2 * kk + 5];
            bf16x8 bp0 = __builtin_bit_cast(bf16x8, bw0);
            bf16x8 bp1 = __builtin_bit_cast(bf16x8, bw1);
#pragma unroll
            for (int mt = 0; mt < 4; ++mt) {
                bf16x8 av = *(const bf16x8*)(VsC + (mt * 16 + col) * 72 + kk * 32 + quad * 8);
                if (d0)
                    o0[mt] = __builtin_amdgcn_mfma_f32_16x16x32_bf16(av, bp0, o0[mt], 0, 0, 0);
                o1[mt] = __builtin_amdgcn_mfma_f32_16x16x32_bf16(av, bp1, o1[mt], 0, 0, 0);
            }
        }
        if (j < t1) {  // deposit prefetched tile j+1 into the other buffer
            int nxt = cur ^ 1;
            *(uint4*)(Ks[nxt] + r0 * 72 + kc * 8) = kr0;
            *(uint4*)(Ks[nxt] + (r0 + 32) * 72 + kc * 8) = kr1;
            *(uint4*)(Vs[nxt] + r0 * 72 + kc * 8) = vr0;
            *(uint4*)(Vs[nxt] + (r0 + 32) * 72 + kc * 8) = vr1;
            __syncthreads();
        }
    }
    l0 += __shfl_xor(l0, 16);
    l0 += __shfl_xor(l0, 32);
    l1 += __shfl_xor(l1, 16);
    l1 += __shfl_xor(l1, 32);
    float inv0 = 1.0f / l0, inv1 = 1.0f / l1;
    u16* orow0 = O + (size_t)(b * 2048 + myq0) * 1024 + h * 64;
    u16* orow1 = O + (size_t)(b * 2048 + myq1) * 1024 + h * 64;
#pragma unroll
    for (int mt = 0; mt < 4; ++mt) {
        uint2 w0, w1;
        w0.x = pk2(o0[mt][0] * inv0, o0[mt][1] * inv0);
        w0.y = pk2(o0[mt][2] * inv0, o0[mt][3] * inv0);
        w1.x = pk2(o1[mt][0] * inv1, o1[mt][1] * inv1);
        w1.y = pk2(o1[mt][2] * inv1, o1[mt][3] * inv1);
        *(uint2*)(orow0 + mt * 16 + quad * 4) = w0;
        *(uint2*)(orow1 + mt * 16 + quad * 4) = w1;
    }
}

// ---------------- output projection GEMM ----------------
__global__ __launch_bounds__(256) void k_gemm_proj(const u16* __restrict__ A,
                                                   const u16* __restrict__ Bt,
                                                   const float* __restrict__ bias,
                                                   float* __restrict__ out) {
    __shared__ __align__(16) u16 As[2 * 128 * 32];
    __shared__ __align__(16) u16 Bs[2 * 128 * 32];
    const int K = 1024;
    int tid = threadIdx.x;
    int lane = tid & 63, wave = tid >> 6;
    int col = lane & 15, quad = lane >> 4;
    int wm = wave >> 1, wn = wave & 1;
    int mBase = blockIdx.y * 128;
    int nBase = blockIdx.x * 128;
    f32x4 acc[4][4] = {};
    gemm_mainloop(A + (size_t)mBase * K, Bt + (size_t)nBase * K, K, As, Bs, tid, acc);
#pragma unroll
    for (int nt = 0; nt < 4; ++nt) {
        int n = nBase + wn * 64 + nt * 16 + col;
        float bv = bias[n];
#pragma unroll
        for (int mt = 0; mt < 4; ++mt) {
            int m = mBase + wm * 64 + mt * 16 + quad * 4;
#pragma unroll
            for (int r = 0; r < 4; ++r)
                out[(size_t)(m + r) * 1024 + n] = acc[mt][nt][r] + bv;
        }
    }
}

// ---------------- launch ----------------
// ws: x_bf@0 (16MB) wqkvT (6MB) wprojT (2MB) Qr Kr Vt AO (16MB each)
// rope table (512KB) aliases AO: consumed by qkv gemm, AO written later by attn.
extern "C" void kernel_launch(void* const* d_in, const int* in_sizes, int n_in,
                              void* d_out, int out_size, void* d_ws, size_t ws_size,
                              hipStream_t stream) {
    const float* x = (const float*)d_in[0];
    const float* w_qkv = (const float*)d_in[1];
    const float* b_qkv = (const float*)d_in[2];
    const float* w_proj = (const float*)d_in[3];
    const float* b_proj = (const float*)d_in[4];
    float* out = (float*)d_out;
    char* ws = (char*)d_ws;
    u16* x_bf = (u16*)(ws);
    u16* wqkvT = (u16*)(ws + 16777216);
    u16* wprojT = (u16*)(ws + 23068672);
    u16* Qr = (u16*)(ws + 25165824);
    u16* Kr = (u16*)(ws + 41943040);
    u16* Vt = (u16*)(ws + 58720256);
    u16* AO = (u16*)(ws + 75497472);
    float2* tab = (float2*)(ws + 75497472);  // alias AO (dead until k_attn)

    k_rope_table<<<256, 256, 0, stream>>>(tab);
    k_convert<<<4096, 256, 0, stream>>>(x, x_bf, 1048576);
    k_transpose_bf16<<<dim3(48, 16), 256, 0, stream>>>(w_qkv, wqkvT, 1024, 3072);
    k_transpose_bf16<<<dim3(16, 16), 256, 0, stream>>>(w_proj, wprojT, 1024, 1024);
    k_gemm_qkv_rope<<<dim3(24, 64), 256, 0, stream>>>(x_bf, wqkvT, b_qkv, tab, Qr, Kr, Vt);
    k_attn<<<dim3(16, 64), 256, 0, stream>>>(Qr, Kr, Vt, AO);
    k_gemm_proj<<<dim3(8, 64), 256, 0, stream>>>(AO, wprojT, b_proj, out);
}

// Round 3
// 256.281 us; speedup vs baseline: 1.0942x; 1.0942x over previous
//
#include <hip/hip_runtime.h>

typedef unsigned short u16;
typedef __bf16 bf16x8 __attribute__((ext_vector_type(8)));
typedef float f32x4 __attribute__((ext_vector_type(4)));

__device__ __forceinline__ u16 f2b(float f) {
    unsigned u = __builtin_bit_cast(unsigned, f);
    unsigned r = (u + 0x7fffu + ((u >> 16) & 1u)) >> 16;
    return (u16)r;
}
#if __has_builtin(__builtin_amdgcn_cvt_pk_bf16_f32)
typedef __bf16 bf16x2_t __attribute__((ext_vector_type(2)));
__device__ __forceinline__ unsigned pk2(float a, float b) {
    return __builtin_bit_cast(unsigned, __builtin_amdgcn_cvt_pk_bf16_f32(a, b));
}
#else
__device__ __forceinline__ unsigned pk2(float a, float b) {
    return (unsigned)f2b(a) | ((unsigned)f2b(b) << 16);
}
#endif
#if __has_builtin(__builtin_amdgcn_exp2f)
#define EXP2F(x) __builtin_amdgcn_exp2f(x)
#else
#define EXP2F(x) exp2f(x)
#endif

// async global->LDS 16B/lane; lds dest is wave-uniform base (+lane*16 by HW)
__device__ __forceinline__ void gl_lds16(const u16* g, u16* l) {
    __builtin_amdgcn_global_load_lds(
        (const __attribute__((address_space(1))) unsigned*)(const void*)g,
        (__attribute__((address_space(3))) unsigned*)(void*)l, 16, 0, 0);
}

// ---------------- RoPE cos/sin table: tab[s*32+d] = (cos, sin)(s * 10000^(-d/32)) ----
__global__ __launch_bounds__(256) void k_rope_table(float2* __restrict__ tab) {
    int i = blockIdx.x * 256 + threadIdx.x;  // 0..65535
    int s = i >> 5, d = i & 31;
    const float C0 = 0.4152410118609203f;  // log2(10000)/32
    float inv_freq = exp2f(-C0 * (float)d);
    float sn, cs;
    sincosf((float)s * inv_freq, &sn, &cs);
    tab[i] = make_float2(cs, sn);
}

// ---------------- convert x (fp32 -> bf16), 8 elems/thread ----------------
__global__ __launch_bounds__(256) void k_convert(const float* __restrict__ in,
                                                 u16* __restrict__ out, int n8) {
    int i = blockIdx.x * 256 + threadIdx.x;
    if (i >= n8) return;
    const float4* p = (const float4*)(in + (size_t)i * 8);
    float4 a = p[0], b = p[1];
    u16 t[8] = {f2b(a.x), f2b(a.y), f2b(a.z), f2b(a.w),
                f2b(b.x), f2b(b.y), f2b(b.z), f2b(b.w)};
    *(uint4*)(out + (size_t)i * 8) = *(const uint4*)t;
}

// -------- transpose + convert: in[R][C] fp32 -> out[C][R] bf16, 64x64 tiles --------
__global__ __launch_bounds__(256) void k_transpose_bf16(const float* __restrict__ in,
                                                        u16* __restrict__ out,
                                                        int R, int C) {
    __shared__ u16 tile[64][72];
    int tc = blockIdx.x * 64;
    int tr = blockIdx.y * 64;
    for (int i = threadIdx.x; i < 4096; i += 256) {
        int r = i >> 6, c = i & 63;
        tile[c][r] = f2b(in[(size_t)(tr + r) * C + tc + c]);
    }
    __syncthreads();
    for (int i = threadIdx.x; i < 4096; i += 256) {
        int r = i >> 6, c = i & 63;
        out[(size_t)(tc + r) * R + tr + c] = tile[r][c];
    }
}

// ------- 128x128xK bf16 MFMA mainloop, BK=64 (2x32 stages per barrier pair) -------
// LDS: two 128x32 subtiles per operand (32 KB total), unpadded for DMA deposit.
__device__ __forceinline__ void gemm_mainloop(const u16* __restrict__ Ab,
                                              const u16* __restrict__ Bb, int K,
                                              u16* As, u16* Bs, int tid,
                                              f32x4 (&acc)[4][4]) {
    const int wave = tid >> 6, lane = tid & 63;
    const int col = lane & 15, quad = lane >> 4;
    const int wm = wave >> 1, wn = wave & 1;
    const int lrow = lane >> 2, lk = (lane & 3) * 8;
    u16* ldsA0 = As + (wave * 16) * 32;  // wave-uniform segment bases
    u16* ldsA1 = As + (64 + wave * 16) * 32;
    u16* ldsB0 = Bs + (wave * 16) * 32;
    u16* ldsB1 = Bs + (64 + wave * 16) * 32;
    const u16* gA0 = Ab + (size_t)(wave * 16 + lrow) * K + lk;
    const u16* gA1 = gA0 + (size_t)64 * K;
    const u16* gB0 = Bb + (size_t)(wave * 16 + lrow) * K + lk;
    const u16* gB1 = gB0 + (size_t)64 * K;
    for (int k0 = 0; k0 < K; k0 += 64) {
        if (k0) __syncthreads();
#pragma unroll
        for (int kh = 0; kh < 2; ++kh) {
            int ko = k0 + kh * 32;
            gl_lds16(gA0 + ko, ldsA0 + kh * 4096);
            gl_lds16(gA1 + ko, ldsA1 + kh * 4096);
            gl_lds16(gB0 + ko, ldsB0 + kh * 4096);
            gl_lds16(gB1 + ko, ldsB1 + kh * 4096);
        }
        __syncthreads();  // compiler drains vmcnt(0) before s_barrier
#pragma unroll
        for (int kh = 0; kh < 2; ++kh) {
            bf16x8 af[4], bfr[4];
#pragma unroll
            for (int mt = 0; mt < 4; ++mt)
                af[mt] = *(const bf16x8*)(As + kh * 4096 +
                                          (wm * 64 + mt * 16 + col) * 32 + quad * 8);
#pragma unroll
            for (int nt = 0; nt < 4; ++nt)
                bfr[nt] = *(const bf16x8*)(Bs + kh * 4096 +
                                           (wn * 64 + nt * 16 + col) * 32 + quad * 8);
#pragma unroll
            for (int mt = 0; mt < 4; ++mt)
#pragma unroll
                for (int nt = 0; nt < 4; ++nt)
                    acc[mt][nt] = __builtin_amdgcn_mfma_f32_16x16x32_bf16(
                        af[mt], bfr[nt], acc[mt][nt], 0, 0, 0);
        }
    }
}

// ---------------- QKV GEMM + bias + RoPE + head reshape ----------------
// Q additionally prescaled by 0.125*log2(e) so attention softmax is pure exp2.
// Region (q/k/v) is block-uniform: 128-col blocks never straddle a 1024 boundary.
// Q/K epilogue: RoPE via precomputed table, stage rotated bf16 tile in LDS
// (reusing the 32KB mainloop buffers, 16B-chunk XOR swizzle), then 16B/lane
// coalesced stores. V epilogue: 4 consecutive-s values packed per 8B store.
__global__ __launch_bounds__(256) void k_gemm_qkv_rope(
    const u16* __restrict__ A, const u16* __restrict__ Bt,
    const float* __restrict__ bias, const float2* __restrict__ tab,
    u16* __restrict__ Qr, u16* __restrict__ Kr, u16* __restrict__ Vt) {
    __shared__ __align__(16) u16 smem[16384];  // mainloop: As|Bs ; epilogue: 128x128 tile
    u16* As = smem;
    u16* Bs = smem + 8192;
    const int K = 1024;
    int tid = threadIdx.x;
    int lane = tid & 63, wave = tid >> 6;
    int col = lane & 15, quad = lane >> 4;
    int wm = wave >> 1, wn = wave & 1;
    int mBase = blockIdx.y * 128;
    int nBase = blockIdx.x * 128;
    f32x4 acc[4][4] = {};
    gemm_mainloop(A + (size_t)mBase * K, Bt + (size_t)nBase * K, K, As, Bs, tid, acc);

    int region = nBase >> 10;  // 0=q, 1=k, 2=v (block-uniform)
    int n64 = nBase + wn * 64;
    int h = (n64 & 1023) >> 6;
    if (region < 2) {
        __syncthreads();  // mainloop LDS reads complete before tile overwrite
        float qs = (region == 0) ? 0.18033688011112042f : 1.0f;  // 0.125*log2(e)
#pragma unroll
        for (int nt = 0; nt < 2; ++nt) {
            int d1 = nt * 16 + col;  // 0..31
            float b1 = bias[n64 + d1];
            float b2 = bias[n64 + d1 + 32];
            int nl = wn * 64 + nt * 16 + col;
#pragma unroll
            for (int mt = 0; mt < 4; ++mt) {
                int mlb = wm * 64 + mt * 16 + quad * 4;
#pragma unroll
                for (int r = 0; r < 4; ++r) {
                    int mloc = mlb + r;
                    int s = (mBase + mloc) & 2047;
                    float2 t = tab[s * 32 + d1];
                    float t1 = acc[mt][nt][r] + b1;
                    float t2 = acc[mt][nt + 2][r] + b2;
                    int sw = (mloc & 7) << 3;  // 16B-chunk XOR swizzle
                    smem[mloc * 128 + (nl ^ sw)] = f2b((t1 * t.x - t2 * t.y) * qs);
                    smem[mloc * 128 + ((nl + 32) ^ sw)] = f2b((t2 * t.x + t1 * t.y) * qs);
                }
            }
        }
        __syncthreads();
        u16* outp = (region == 0) ? Qr : Kr;
#pragma unroll
        for (int p = 0; p < 8; ++p) {
            int lin = p * 256 + tid;   // 0..2047
            int mloc = lin >> 4;       // 0..127
            int c8 = (lin & 15) << 3;  // 0..120
            uint4 v = *(const uint4*)(smem + mloc * 128 + (c8 ^ ((mloc & 7) << 3)));
            int m = mBase + mloc;
            int s = m & 2047, b = m >> 11;
            int ng = (nBase & 1023) + c8;  // col within region
            *(uint4*)(Qr == outp || Kr == outp
                          ? outp + ((size_t)((b * 16 + (ng >> 6)) * 2048 + s)) * 64 +
                                (ng & 63)
                          : outp) = v;
        }
    } else {
        int b = mBase >> 11;     // block-uniform (mBase multiple of 128)
        int sb0 = mBase & 2047;  // s of tile row 0
#pragma unroll
        for (int nt = 0; nt < 4; ++nt) {
            int d = nt * 16 + col;
            float bv = bias[n64 + d];
            u16* vrow = Vt + ((size_t)((b * 16 + h) * 64 + d)) * 2048;
#pragma unroll
            for (int mt = 0; mt < 4; ++mt) {
                int s = sb0 + wm * 64 + mt * 16 + quad * 4;  // 4-aligned
                uint2 w;
                w.x = pk2(acc[mt][nt][0] + bv, acc[mt][nt][1] + bv);
                w.y = pk2(acc[mt][nt][2] + bv, acc[mt][nt][3] + bv);
                *(uint2*)(vrow + s) = w;
            }
        }
    }
}

// ------------- flash attention (causal, transposed, permuted-row) -------------
// One block = one PAIR of 64-query tiles processed sequentially: phase 0 handles
// tile T=31-t (33-t key-tile iters incl. prologue), phase 1 handles T=t. Every
// block does exactly 33 key-tile iterations -> uniform work, no straggler tail
// (round-2 lesson: per-qb blocks spread 2..32 iters; exact-fit grid has no
// backfill, so heavy CUs ran near-solo while the chip idled).
// Grid 16x64 = 1024 blocks = 4/CU co-resident (LDS 36KB -> 4 blocks max).
// XCD map: xcd=id&7, w=id>>3, head=xcd*8+(w&7), t=w>>3 -- a head's 16 blocks
// share one XCD's L2 (round-2 win: FETCH 147->31MB); same-CU blocks (stride-32
// round-robin within XCD) share a head.
// Per phase: wave owns 16 q rows (myq=T*64+wave*16+col). K/V double-buffered
// (T14): tile j+1's global loads issue before tile j's compute, deposit to the
// other LDS buffer after compute, ONE barrier per iter.
// Permuted-row QK^T: tile nt reads Ks row (nt&1)*32+(col>>2)*8+(nt>>1)*4+(col&3)
// so lane reg (nt,r) holds key (nt&1)*32+quad*8+(nt>>1)*4+r => PV B-frag is
// lane-local: {P4[2kk],P4[2kk+1],P4[2kk+4],P4[2kk+5]}. Fixed-max softmax (Q
// prescaled by 0.125*log2(e) upstream; probs = exp2(s), sum reduced at end).
__global__ __launch_bounds__(256, 4) void k_attn(const u16* __restrict__ Qr,
                                                 const u16* __restrict__ Kr,
                                                 const u16* __restrict__ Vt,
                                                 u16* __restrict__ O) {
    __shared__ __align__(16) u16 Ks[2][64 * 72];  // [buf][key][d]
    __shared__ __align__(16) u16 Vs[2][64 * 72];  // [buf][d][key]
    int tid = threadIdx.x, wave = tid >> 6, lane = tid & 63;
    int col = lane & 15, quad = lane >> 4;
    int id = blockIdx.x + (blockIdx.y << 4);
    int xcd = id & 7, w = id >> 3;    // w: 0..127 within XCD
    int head = xcd * 8 + (w & 7);     // 0..63
    int tsel = w >> 3;                // 0..15
    int b = head >> 4, h = head & 15;
    size_t headQ = (size_t)head * 2048 * 64;
    size_t headV = (size_t)head * 64 * 2048;
    int r0 = tid >> 3, kc = tid & 7;
    int rb72 = ((col >> 2) * 8 + (col & 3)) * 72;  // permuted row base
    const u16* kg0 = Kr + headQ + (size_t)r0 * 64 + kc * 8;
    const u16* vg0 = Vt + headV + (size_t)r0 * 2048 + kc * 8;

#pragma unroll 1
    for (int phase = 0; phase < 2; ++phase) {
        int T = phase ? tsel : 31 - tsel;  // key-tile count-1 for this q-tile
        int myq = T * 64 + wave * 16 + col;
        const u16* qp = Qr + headQ + (size_t)myq * 64;
        bf16x8 aq0 = *(const bf16x8*)(qp + quad * 8);
        bf16x8 aq1 = *(const bf16x8*)(qp + 32 + quad * 8);
        f32x4 o[4] = {};
        float l = 0.f;

        __syncthreads();  // prior phase's LDS reads complete before re-staging
        {                 // prologue: stage key-tile 0 into buf 0
            uint4 a0 = *(const uint4*)kg0;
            uint4 a1 = *(const uint4*)(kg0 + 32 * 64);
            uint4 v0 = *(const uint4*)vg0;
            uint4 v1 = *(const uint4*)(vg0 + 32 * 2048);
            *(uint4*)(Ks[0] + r0 * 72 + kc * 8) = a0;
            *(uint4*)(Ks[0] + (r0 + 32) * 72 + kc * 8) = a1;
            *(uint4*)(Vs[0] + r0 * 72 + kc * 8) = v0;
            *(uint4*)(Vs[0] + (r0 + 32) * 72 + kc * 8) = v1;
        }
        __syncthreads();

        for (int j = 0; j <= T; ++j) {
            int cur = j & 1;
            uint4 kr0, kr1, vr0, vr1;
            if (j < T) {  // issue next tile's loads; deposited after compute
                const u16* kgn = kg0 + (size_t)(j + 1) * 64 * 64;
                const u16* vgn = vg0 + (j + 1) * 64;
                kr0 = *(const uint4*)kgn;
                kr1 = *(const uint4*)(kgn + 32 * 64);
                vr0 = *(const uint4*)vgn;
                vr1 = *(const uint4*)(vgn + 32 * 2048);
            }
            const u16* KsC = Ks[cur];
            const u16* VsC = Vs[cur];
            f32x4 s[4];
#pragma unroll
            for (int nt = 0; nt < 4; ++nt) {
                const u16* kp = KsC + rb72 + ((nt & 1) * 32 + (nt >> 1) * 4) * 72;
                bf16x8 ak0 = *(const bf16x8*)(kp + quad * 8);
                bf16x8 ak1 = *(const bf16x8*)(kp + 32 + quad * 8);
                f32x4 z = {};
                z = __builtin_amdgcn_mfma_f32_16x16x32_bf16(ak0, aq0, z, 0, 0, 0);
                s[nt] = __builtin_amdgcn_mfma_f32_16x16x32_bf16(ak1, aq1, z, 0, 0, 0);
            }
            if (j == T) {  // diagonal mask
#pragma unroll
                for (int nt = 0; nt < 4; ++nt) {
                    int keyb = j * 64 + (nt & 1) * 32 + quad * 8 + (nt >> 1) * 4;
#pragma unroll
                    for (int r = 0; r < 4; ++r)
                        if (keyb + r > myq) s[nt][r] = -3.0e38f;
                }
            }
            unsigned P4[8];
#pragma unroll
            for (int nt = 0; nt < 4; ++nt) {
                float p0 = EXP2F(s[nt][0]);
                float p1 = EXP2F(s[nt][1]);
                float p2 = EXP2F(s[nt][2]);
                float p3 = EXP2F(s[nt][3]);
                l += (p0 + p1) + (p2 + p3);
                P4[2 * nt] = pk2(p0, p1);
                P4[2 * nt + 1] = pk2(p2, p3);
            }
#pragma unroll
            for (int kk = 0; kk < 2; ++kk) {
                uint4 bw;
                bw.x = P4[2 * kk];
                bw.y = P4[2 * kk + 1];
                bw.z = P4[2 * kk + 4];
                bw.w = P4[2 * kk + 5];
                bf16x8 bp = __builtin_bit_cast(bf16x8, bw);
#pragma unroll
                for (int mt = 0; mt < 4; ++mt) {
                    bf16x8 av = *(const bf16x8*)(VsC + (mt * 16 + col) * 72 + kk * 32 + quad * 8);
                    o[mt] = __builtin_amdgcn_mfma_f32_16x16x32_bf16(av, bp, o[mt], 0, 0, 0);
                }
            }
            if (j < T) {  // deposit prefetched tile j+1 into the other buffer
                int nxt = cur ^ 1;
                *(uint4*)(Ks[nxt] + r0 * 72 + kc * 8) = kr0;
                *(uint4*)(Ks[nxt] + (r0 + 32) * 72 + kc * 8) = kr1;
                *(uint4*)(Vs[nxt] + r0 * 72 + kc * 8) = vr0;
                *(uint4*)(Vs[nxt] + (r0 + 32) * 72 + kc * 8) = vr1;
                __syncthreads();
            }
        }
        l += __shfl_xor(l, 16);
        l += __shfl_xor(l, 32);
        float inv = 1.0f / l;
        u16* orow = O + (size_t)(b * 2048 + myq) * 1024 + h * 64;
#pragma unroll
        for (int mt = 0; mt < 4; ++mt) {
            uint2 w2;
            w2.x = pk2(o[mt][0] * inv, o[mt][1] * inv);
            w2.y = pk2(o[mt][2] * inv, o[mt][3] * inv);
            *(uint2*)(orow + mt * 16 + quad * 4) = w2;
        }
    }
}

// ---------------- output projection GEMM ----------------
__global__ __launch_bounds__(256) void k_gemm_proj(const u16* __restrict__ A,
                                                   const u16* __restrict__ Bt,
                                                   const float* __restrict__ bias,
                                                   float* __restrict__ out) {
    __shared__ __align__(16) u16 As[2 * 128 * 32];
    __shared__ __align__(16) u16 Bs[2 * 128 * 32];
    const int K = 1024;
    int tid = threadIdx.x;
    int lane = tid & 63, wave = tid >> 6;
    int col = lane & 15, quad = lane >> 4;
    int wm = wave >> 1, wn = wave & 1;
    int mBase = blockIdx.y * 128;
    int nBase = blockIdx.x * 128;
    f32x4 acc[4][4] = {};
    gemm_mainloop(A + (size_t)mBase * K, Bt + (size_t)nBase * K, K, As, Bs, tid, acc);
#pragma unroll
    for (int nt = 0; nt < 4; ++nt) {
        int n = nBase + wn * 64 + nt * 16 + col;
        float bv = bias[n];
#pragma unroll
        for (int mt = 0; mt < 4; ++mt) {
            int m = mBase + wm * 64 + mt * 16 + quad * 4;
#pragma unroll
            for (int r = 0; r < 4; ++r)
                out[(size_t)(m + r) * 1024 + n] = acc[mt][nt][r] + bv;
        }
    }
}

// ---------------- launch ----------------
// ws: x_bf@0 (16MB) wqkvT (6MB) wprojT (2MB) Qr Kr Vt AO (16MB each)
// rope table (512KB) aliases AO: consumed by qkv gemm, AO written later by attn.
extern "C" void kernel_launch(void* const* d_in, const int* in_sizes, int n_in,
                              void* d_out, int out_size, void* d_ws, size_t ws_size,
                              hipStream_t stream) {
    const float* x = (const float*)d_in[0];
    const float* w_qkv = (const float*)d_in[1];
    const float* b_qkv = (const float*)d_in[2];
    const float* w_proj = (const float*)d_in[3];
    const float* b_proj = (const float*)d_in[4];
    float* out = (float*)d_out;
    char* ws = (char*)d_ws;
    u16* x_bf = (u16*)(ws);
    u16* wqkvT = (u16*)(ws + 16777216);
    u16* wprojT = (u16*)(ws + 23068672);
    u16* Qr = (u16*)(ws + 25165824);
    u16* Kr = (u16*)(ws + 41943040);
    u16* Vt = (u16*)(ws + 58720256);
    u16* AO = (u16*)(ws + 75497472);
    float2* tab = (float2*)(ws + 75497472);  // alias AO (dead until k_attn)

    k_rope_table<<<256, 256, 0, stream>>>(tab);
    k_convert<<<4096, 256, 0, stream>>>(x, x_bf, 1048576);
    k_transpose_bf16<<<dim3(48, 16), 256, 0, stream>>>(w_qkv, wqkvT, 1024, 3072);
    k_transpose_bf16<<<dim3(16, 16), 256, 0, stream>>>(w_proj, wprojT, 1024, 1024);
    k_gemm_qkv_rope<<<dim3(24, 64), 256, 0, stream>>>(x_bf, wqkvT, b_qkv, tab, Qr, Kr, Vt);
    k_attn<<<dim3(16, 64), 256, 0, stream>>>(Qr, Kr, Vt, AO);
    k_gemm_proj<<<dim3(8, 64), 256, 0, stream>>>(AO, wprojT, b_proj, out);
}

// Round 4
// 244.683 us; speedup vs baseline: 1.1461x; 1.0474x over previous
//
#include <hip/hip_runtime.h>

typedef unsigned short u16;
typedef __bf16 bf16x8 __attribute__((ext_vector_type(8)));
typedef float f32x4 __attribute__((ext_vector_type(4)));

__device__ __forceinline__ u16 f2b(float f) {
    unsigned u = __builtin_bit_cast(unsigned, f);
    unsigned r = (u + 0x7fffu + ((u >> 16) & 1u)) >> 16;
    return (u16)r;
}
#if __has_builtin(__builtin_amdgcn_cvt_pk_bf16_f32)
typedef __bf16 bf16x2_t __attribute__((ext_vector_type(2)));
__device__ __forceinline__ unsigned pk2(float a, float b) {
    return __builtin_bit_cast(unsigned, __builtin_amdgcn_cvt_pk_bf16_f32(a, b));
}
#else
__device__ __forceinline__ unsigned pk2(float a, float b) {
    return (unsigned)f2b(a) | ((unsigned)f2b(b) << 16);
}
#endif
#if __has_builtin(__builtin_amdgcn_exp2f)
#define EXP2F(x) __builtin_amdgcn_exp2f(x)
#else
#define EXP2F(x) exp2f(x)
#endif

// async global->LDS 16B/lane; lds dest is wave-uniform base (+lane*16 by HW);
// global source IS per-lane (m173) -- swizzled layouts via pre-swizzled source.
__device__ __forceinline__ void gl_lds16(const u16* g, u16* l) {
    __builtin_amdgcn_global_load_lds(
        (const __attribute__((address_space(1))) unsigned*)(const void*)g,
        (__attribute__((address_space(3))) unsigned*)(void*)l, 16, 0, 0);
}

// -------- 64x64 transpose+convert helper: in[R][C] f32 -> out[C][R] bf16 --------
__device__ __forceinline__ void transpose64(const float* __restrict__ in,
                                            u16* __restrict__ out, int R, int C,
                                            int tr, int tc, int tid, u16 (*tile)[72]) {
    for (int i = tid; i < 4096; i += 256) {
        int r = i >> 6, c = i & 63;
        tile[c][r] = f2b(in[(size_t)(tr + r) * C + tc + c]);
    }
    __syncthreads();
    for (int i = tid; i < 4096; i += 256) {
        int r = i >> 6, c = i & 63;
        out[(size_t)(tc + r) * R + tr + c] = tile[r][c];
    }
}

// ---------------- fused prep: convert x | transpose wqkv | transpose wproj | rope tab ----
// One launch instead of four (launch-gap elimination; tasks are independent,
// branch is block-uniform). Blocks: [0,4096) convert, [4096,4864) wqkvT,
// [4864,5120) wprojT, [5120,5376) rope table.
__global__ __launch_bounds__(256) void k_prep(const float* __restrict__ x,
                                              u16* __restrict__ x_bf,
                                              const float* __restrict__ w_qkv,
                                              u16* __restrict__ wqkvT,
                                              const float* __restrict__ w_proj,
                                              u16* __restrict__ wprojT,
                                              float2* __restrict__ tab) {
    __shared__ u16 tile[64][72];
    int bid = blockIdx.x, tid = threadIdx.x;
    if (bid < 4096) {  // x: fp32 -> bf16, 8 elems/thread
        int i = bid * 256 + tid;
        const float4* p = (const float4*)(x + (size_t)i * 8);
        float4 a = p[0], b = p[1];
        u16 t[8] = {f2b(a.x), f2b(a.y), f2b(a.z), f2b(a.w),
                    f2b(b.x), f2b(b.y), f2b(b.z), f2b(b.w)};
        *(uint4*)(x_bf + (size_t)i * 8) = *(const uint4*)t;
    } else if (bid < 4864) {  // w_qkv [1024][3072] -> wqkvT [3072][1024]
        int q = bid - 4096;
        transpose64(w_qkv, wqkvT, 1024, 3072, (q / 48) * 64, (q % 48) * 64, tid, tile);
    } else if (bid < 5120) {  // w_proj [1024][1024] -> wprojT
        int q = bid - 4864;
        transpose64(w_proj, wprojT, 1024, 1024, (q / 16) * 64, (q % 16) * 64, tid, tile);
    } else {  // tab[s*32+d] = (cos,sin)(s * 10000^(-d/32))
        int i = (bid - 5120) * 256 + tid;  // 0..65535
        int s = i >> 5, d = i & 31;
        const float C0 = 0.4152410118609203f;  // log2(10000)/32
        float inv_freq = exp2f(-C0 * (float)d);
        float sn, cs;
        sincosf((float)s * inv_freq, &sn, &cs);
        tab[i] = make_float2(cs, sn);
    }
}

// ------- 128x128xK bf16 MFMA mainloop, BK=64 (2x32 stages per barrier pair) -------
// LDS: two 128x32 subtiles per operand (32 KB total), unpadded for DMA deposit.
__device__ __forceinline__ void gemm_mainloop(const u16* __restrict__ Ab,
                                              const u16* __restrict__ Bb, int K,
                                              u16* As, u16* Bs, int tid,
                                              f32x4 (&acc)[4][4]) {
    const int wave = tid >> 6, lane = tid & 63;
    const int col = lane & 15, quad = lane >> 4;
    const int wm = wave >> 1, wn = wave & 1;
    const int lrow = lane >> 2, lk = (lane & 3) * 8;
    u16* ldsA0 = As + (wave * 16) * 32;  // wave-uniform segment bases
    u16* ldsA1 = As + (64 + wave * 16) * 32;
    u16* ldsB0 = Bs + (wave * 16) * 32;
    u16* ldsB1 = Bs + (64 + wave * 16) * 32;
    const u16* gA0 = Ab + (size_t)(wave * 16 + lrow) * K + lk;
    const u16* gA1 = gA0 + (size_t)64 * K;
    const u16* gB0 = Bb + (size_t)(wave * 16 + lrow) * K + lk;
    const u16* gB1 = gB0 + (size_t)64 * K;
    for (int k0 = 0; k0 < K; k0 += 64) {
        if (k0) __syncthreads();
#pragma unroll
        for (int kh = 0; kh < 2; ++kh) {
            int ko = k0 + kh * 32;
            gl_lds16(gA0 + ko, ldsA0 + kh * 4096);
            gl_lds16(gA1 + ko, ldsA1 + kh * 4096);
            gl_lds16(gB0 + ko, ldsB0 + kh * 4096);
            gl_lds16(gB1 + ko, ldsB1 + kh * 4096);
        }
        __syncthreads();  // compiler drains vmcnt(0) before s_barrier
#pragma unroll
        for (int kh = 0; kh < 2; ++kh) {
            bf16x8 af[4], bfr[4];
#pragma unroll
            for (int mt = 0; mt < 4; ++mt)
                af[mt] = *(const bf16x8*)(As + kh * 4096 +
                                          (wm * 64 + mt * 16 + col) * 32 + quad * 8);
#pragma unroll
            for (int nt = 0; nt < 4; ++nt)
                bfr[nt] = *(const bf16x8*)(Bs + kh * 4096 +
                                           (wn * 64 + nt * 16 + col) * 32 + quad * 8);
#pragma unroll
            for (int mt = 0; mt < 4; ++mt)
#pragma unroll
                for (int nt = 0; nt < 4; ++nt)
                    acc[mt][nt] = __builtin_amdgcn_mfma_f32_16x16x32_bf16(
                        af[mt], bfr[nt], acc[mt][nt], 0, 0, 0);
        }
    }
}

// ---------------- QKV GEMM + bias + RoPE + head reshape ----------------
// Q additionally prescaled by 0.125*log2(e) so attention softmax is pure exp2.
// Region (q/k/v) is block-uniform: 128-col blocks never straddle a 1024 boundary.
// Q/K epilogue: RoPE via precomputed table, stage rotated bf16 tile in LDS
// (reusing the 32KB mainloop buffers, 16B-chunk XOR swizzle), then 16B/lane
// coalesced stores. V epilogue: 4 consecutive-s values packed per 8B store.
__global__ __launch_bounds__(256) void k_gemm_qkv_rope(
    const u16* __restrict__ A, const u16* __restrict__ Bt,
    const float* __restrict__ bias, const float2* __restrict__ tab,
    u16* __restrict__ Qr, u16* __restrict__ Kr, u16* __restrict__ Vt) {
    __shared__ __align__(16) u16 smem[16384];  // mainloop: As|Bs ; epilogue: 128x128 tile
    u16* As = smem;
    u16* Bs = smem + 8192;
    const int K = 1024;
    int tid = threadIdx.x;
    int lane = tid & 63, wave = tid >> 6;
    int col = lane & 15, quad = lane >> 4;
    int wm = wave >> 1, wn = wave & 1;
    int mBase = blockIdx.y * 128;
    int nBase = blockIdx.x * 128;
    f32x4 acc[4][4] = {};
    gemm_mainloop(A + (size_t)mBase * K, Bt + (size_t)nBase * K, K, As, Bs, tid, acc);

    int region = nBase >> 10;  // 0=q, 1=k, 2=v (block-uniform)
    int n64 = nBase + wn * 64;
    int h = (n64 & 1023) >> 6;
    if (region < 2) {
        __syncthreads();  // mainloop LDS reads complete before tile overwrite
        float qs = (region == 0) ? 0.18033688011112042f : 1.0f;  // 0.125*log2(e)
#pragma unroll
        for (int nt = 0; nt < 2; ++nt) {
            int d1 = nt * 16 + col;  // 0..31
            float b1 = bias[n64 + d1];
            float b2 = bias[n64 + d1 + 32];
            int nl = wn * 64 + nt * 16 + col;
#pragma unroll
            for (int mt = 0; mt < 4; ++mt) {
                int mlb = wm * 64 + mt * 16 + quad * 4;
#pragma unroll
                for (int r = 0; r < 4; ++r) {
                    int mloc = mlb + r;
                    int s = (mBase + mloc) & 2047;
                    float2 t = tab[s * 32 + d1];
                    float t1 = acc[mt][nt][r] + b1;
                    float t2 = acc[mt][nt + 2][r] + b2;
                    int sw = (mloc & 7) << 3;  // 16B-chunk XOR swizzle
                    smem[mloc * 128 + (nl ^ sw)] = f2b((t1 * t.x - t2 * t.y) * qs);
                    smem[mloc * 128 + ((nl + 32) ^ sw)] = f2b((t2 * t.x + t1 * t.y) * qs);
                }
            }
        }
        __syncthreads();
        u16* outp = (region == 0) ? Qr : Kr;
#pragma unroll
        for (int p = 0; p < 8; ++p) {
            int lin = p * 256 + tid;   // 0..2047
            int mloc = lin >> 4;       // 0..127
            int c8 = (lin & 15) << 3;  // 0..120
            uint4 v = *(const uint4*)(smem + mloc * 128 + (c8 ^ ((mloc & 7) << 3)));
            int m = mBase + mloc;
            int s = m & 2047, b = m >> 11;
            int ng = (nBase & 1023) + c8;  // col within region
            *(uint4*)(Qr == outp || Kr == outp
                          ? outp + ((size_t)((b * 16 + (ng >> 6)) * 2048 + s)) * 64 +
                                (ng & 63)
                          : outp) = v;
        }
    } else {
        int b = mBase >> 11;     // block-uniform (mBase multiple of 128)
        int sb0 = mBase & 2047;  // s of tile row 0
#pragma unroll
        for (int nt = 0; nt < 4; ++nt) {
            int d = nt * 16 + col;
            float bv = bias[n64 + d];
            u16* vrow = Vt + ((size_t)((b * 16 + h) * 64 + d)) * 2048;
#pragma unroll
            for (int mt = 0; mt < 4; ++mt) {
                int s = sb0 + wm * 64 + mt * 16 + quad * 4;  // 4-aligned
                uint2 w;
                w.x = pk2(acc[mt][nt][0] + bv, acc[mt][nt][1] + bv);
                w.y = pk2(acc[mt][nt][2] + bv, acc[mt][nt][3] + bv);
                *(uint2*)(vrow + s) = w;
            }
        }
    }
}

// ---- attn K/V tile staging: async DMA, chunk-XOR swizzled (rule #21) ----
// LDS layout [64 rows][8 chunks of 16B]; data chunk c of row r sits at LDS
// chunk c ^ key(r). key_K(r) = (r&3)|(((r>>3)&1)<<2), key_V(d) = d&7 -- both
// equal (col&7) on the read side, giving 2-way (free) bank access vs the old
// 72-pad layout's 4-way. Deposit: per wave 4 gl_lds (8 rows each, linear
// dest), per-lane global source pre-swizzled by the same involution.
__device__ __forceinline__ void stage_kv(const u16* __restrict__ Kt,   // +tile row 0
                                         const u16* __restrict__ Vtb,  // +tile col 0
                                         u16* KsB, u16* VsB, int wave, int lane) {
    int lr = lane >> 3;  // row within 8-row segment
    int lc = lane & 7;   // chunk slot
#pragma unroll
    for (int i = 0; i < 2; ++i) {
        int s = wave * 2 + i;  // K segment 0..7
        int r = s * 8 + lr;    // local key row 0..63
        int key = (r & 3) | (((r >> 3) & 1) << 2);
        gl_lds16(Kt + (size_t)r * 64 + ((lc ^ key) << 3), KsB + s * 512);
    }
#pragma unroll
    for (int i = 0; i < 2; ++i) {
        int s = wave * 2 + i;  // V segment 0..7
        int d = s * 8 + lr;    // local d row 0..63
        int key = d & 7;
        gl_lds16(Vtb + (size_t)d * 2048 + ((lc ^ key) << 3), VsB + s * 512);
    }
}

// ------------- flash attention (causal, transposed, permuted-row) -------------
// One block = one PAIR of 64-query tiles processed sequentially: phase 0 handles
// T=31-t, phase 1 handles T=t -> every block does exactly 33 key-tile iters
// (uniform work, no straggler tail). Grid 16x64 = 1024 blocks = 4/CU (LDS 32KB).
// XCD map: xcd=id&7, head=xcd*8+(w&7), t=w>>3 -- a head's 16 blocks share one
// XCD's L2 (FETCH 147->31MB r2 win).
// K/V double-buffered via async gl_lds DMA: tile j+1's 16 DMA ops (4/wave)
// issue before tile j's compute; the end-of-iter __syncthreads drains vmcnt
// -> load latency hides under QK^T+softmax+PV with near-zero VALU cost
// (replaces 8 VMEM + 8 DS ops per THREAD with 4 DMA per WAVE).
// Permuted-row QK^T: tile nt reads K row (nt&1)*32+(nt>>1)*4+perm(col), so
// lane reg (nt,r) holds key (nt&1)*32+quad*8+(nt>>1)*4+r => PV B-frag is
// lane-local. Fixed-max softmax (Q prescaled by 0.125*log2(e); probs=exp2(s)).
// T5 setprio wraps both MFMA clusters (+4-7% attn, m191).
__global__ __launch_bounds__(256, 4) void k_attn(const u16* __restrict__ Qr,
                                                 const u16* __restrict__ Kr,
                                                 const u16* __restrict__ Vt,
                                                 u16* __restrict__ O) {
    __shared__ __align__(16) u16 Ks[2][4096];  // [buf][key][d] chunk-swizzled
    __shared__ __align__(16) u16 Vs[2][4096];  // [buf][d][key] chunk-swizzled
    int tid = threadIdx.x, wave = tid >> 6, lane = tid & 63;
    int col = lane & 15, quad = lane >> 4;
    int id = blockIdx.x + (blockIdx.y << 4);
    int xcd = id & 7, w = id >> 3;  // w: 0..127 within XCD
    int head = xcd * 8 + (w & 7);   // 0..63
    int tsel = w >> 3;              // 0..15
    int b = head >> 4, h = head & 15;
    size_t headQ = (size_t)head * 2048 * 64;
    size_t headV = (size_t)head * 64 * 2048;
    int prow = (col >> 2) * 8 + (col & 3);  // permuted row within 32
    int ck = col & 7;                       // read-side swizzle key

#pragma unroll 1
    for (int phase = 0; phase < 2; ++phase) {
        int T = phase ? tsel : 31 - tsel;  // key-tile count-1 for this q-tile
        int myq = T * 64 + wave * 16 + col;
        const u16* qp = Qr + headQ + (size_t)myq * 64;
        bf16x8 aq0 = *(const bf16x8*)(qp + quad * 8);
        bf16x8 aq1 = *(const bf16x8*)(qp + 32 + quad * 8);
        f32x4 o[4] = {};
        float l = 0.f;

        // prologue: stage key-tile 0 into buf 0 (prev phase ended with barrier)
        stage_kv(Kr + headQ, Vt + headV, Ks[0], Vs[0], wave, lane);
        __syncthreads();  // drains vmcnt(0): tile 0 deposited

        for (int j = 0; j <= T; ++j) {
            int cur = j & 1;
            if (j < T)  // async prefetch tile j+1 into other buffer
                stage_kv(Kr + headQ + ((size_t)(j + 1) << 12),
                         Vt + headV + (j + 1) * 64, Ks[cur ^ 1], Vs[cur ^ 1],
                         wave, lane);
            const u16* KsC = Ks[cur];
            const u16* VsC = Vs[cur];
            f32x4 s[4];
            __builtin_amdgcn_s_setprio(1);
#pragma unroll
            for (int nt = 0; nt < 4; ++nt) {
                const u16* kp = KsC + ((nt & 1) * 32 + (nt >> 1) * 4 + prow) * 64;
                bf16x8 ak0 = *(const bf16x8*)(kp + ((quad ^ ck) << 3));
                bf16x8 ak1 = *(const bf16x8*)(kp + (((quad + 4) ^ ck) << 3));
                f32x4 z = {};
                z = __builtin_amdgcn_mfma_f32_16x16x32_bf16(ak0, aq0, z, 0, 0, 0);
                s[nt] = __builtin_amdgcn_mfma_f32_16x16x32_bf16(ak1, aq1, z, 0, 0, 0);
            }
            __builtin_amdgcn_s_setprio(0);
            if (j == T) {  // diagonal mask
#pragma unroll
                for (int nt = 0; nt < 4; ++nt) {
                    int keyb = j * 64 + (nt & 1) * 32 + quad * 8 + (nt >> 1) * 4;
#pragma unroll
                    for (int r = 0; r < 4; ++r)
                        if (keyb + r > myq) s[nt][r] = -3.0e38f;
                }
            }
            unsigned P4[8];
#pragma unroll
            for (int nt = 0; nt < 4; ++nt) {
                float p0 = EXP2F(s[nt][0]);
                float p1 = EXP2F(s[nt][1]);
                float p2 = EXP2F(s[nt][2]);
                float p3 = EXP2F(s[nt][3]);
                l += (p0 + p1) + (p2 + p3);
                P4[2 * nt] = pk2(p0, p1);
                P4[2 * nt + 1] = pk2(p2, p3);
            }
            __builtin_amdgcn_s_setprio(1);
#pragma unroll
            for (int kk = 0; kk < 2; ++kk) {
                uint4 bw;
                bw.x = P4[2 * kk];
                bw.y = P4[2 * kk + 1];
                bw.z = P4[2 * kk + 4];
                bw.w = P4[2 * kk + 5];
                bf16x8 bp = __builtin_bit_cast(bf16x8, bw);
#pragma unroll
                for (int mt = 0; mt < 4; ++mt) {
                    bf16x8 av = *(const bf16x8*)(VsC + (mt * 16 + col) * 64 +
                                                 (((kk * 4 + quad) ^ ck) << 3));
                    o[mt] = __builtin_amdgcn_mfma_f32_16x16x32_bf16(av, bp, o[mt], 0, 0, 0);
                }
            }
            __builtin_amdgcn_s_setprio(0);
            __syncthreads();  // drains prefetch DMA + releases buffers
        }
        l += __shfl_xor(l, 16);
        l += __shfl_xor(l, 32);
        float inv = 1.0f / l;
        u16* orow = O + (size_t)(b * 2048 + myq) * 1024 + h * 64;
#pragma unroll
        for (int mt = 0; mt < 4; ++mt) {
            uint2 w2;
            w2.x = pk2(o[mt][0] * inv, o[mt][1] * inv);
            w2.y = pk2(o[mt][2] * inv, o[mt][3] * inv);
            *(uint2*)(orow + mt * 16 + quad * 4) = w2;
        }
    }
}

// ---------------- output projection GEMM ----------------
__global__ __launch_bounds__(256) void k_gemm_proj(const u16* __restrict__ A,
                                                   const u16* __restrict__ Bt,
                                                   const float* __restrict__ bias,
                                                   float* __restrict__ out) {
    __shared__ __align__(16) u16 As[2 * 128 * 32];
    __shared__ __align__(16) u16 Bs[2 * 128 * 32];
    const int K = 1024;
    int tid = threadIdx.x;
    int lane = tid & 63, wave = tid >> 6;
    int col = lane & 15, quad = lane >> 4;
    int wm = wave >> 1, wn = wave & 1;
    int mBase = blockIdx.y * 128;
    int nBase = blockIdx.x * 128;
    f32x4 acc[4][4] = {};
    gemm_mainloop(A + (size_t)mBase * K, Bt + (size_t)nBase * K, K, As, Bs, tid, acc);
#pragma unroll
    for (int nt = 0; nt < 4; ++nt) {
        int n = nBase + wn * 64 + nt * 16 + col;
        float bv = bias[n];
#pragma unroll
        for (int mt = 0; mt < 4; ++mt) {
            int m = mBase + wm * 64 + mt * 16 + quad * 4;
#pragma unroll
            for (int r = 0; r < 4; ++r)
                out[(size_t)(m + r) * 1024 + n] = acc[mt][nt][r] + bv;
        }
    }
}

// ---------------- launch ----------------
// ws: x_bf@0 (16MB) wqkvT (6MB) wprojT (2MB) Qr Kr Vt AO (16MB each)
// rope table (512KB) aliases AO: consumed by qkv gemm, AO written later by attn.
extern "C" void kernel_launch(void* const* d_in, const int* in_sizes, int n_in,
                              void* d_out, int out_size, void* d_ws, size_t ws_size,
                              hipStream_t stream) {
    const float* x = (const float*)d_in[0];
    const float* w_qkv = (const float*)d_in[1];
    const float* b_qkv = (const float*)d_in[2];
    const float* w_proj = (const float*)d_in[3];
    const float* b_proj = (const float*)d_in[4];
    float* out = (float*)d_out;
    char* ws = (char*)d_ws;
    u16* x_bf = (u16*)(ws);
    u16* wqkvT = (u16*)(ws + 16777216);
    u16* wprojT = (u16*)(ws + 23068672);
    u16* Qr = (u16*)(ws + 25165824);
    u16* Kr = (u16*)(ws + 41943040);
    u16* Vt = (u16*)(ws + 58720256);
    u16* AO = (u16*)(ws + 75497472);
    float2* tab = (float2*)(ws + 75497472);  // alias AO (dead until k_attn)

    k_prep<<<5376, 256, 0, stream>>>(x, x_bf, w_qkv, wqkvT, w_proj, wprojT, tab);
    k_gemm_qkv_rope<<<dim3(24, 64), 256, 0, stream>>>(x_bf, wqkvT, b_qkv, tab, Qr, Kr, Vt);
    k_attn<<<dim3(16, 64), 256, 0, stream>>>(Qr, Kr, Vt, AO);
    k_gemm_proj<<<dim3(8, 64), 256, 0, stream>>>(AO, wprojT, b_proj, out);
}